// Round 14
// baseline (1716.266 us; speedup 1.0000x reference)
//
#include <hip/hip_runtime.h>

typedef _Float16 f16;
typedef __attribute__((ext_vector_type(8))) short short8;
typedef __attribute__((ext_vector_type(8))) _Float16 half8;
typedef __attribute__((ext_vector_type(4))) float f32x4;

#define DEV __device__ __forceinline__

DEV float h2f(short s) { f16 h; __builtin_memcpy(&h, &s, 2); return (float)h; }
DEV short f2h(float f) { f16 h = (f16)f; short s; __builtin_memcpy(&s, &h, 2); return s; }
DEV half8 s2h8(short8 s) { half8 h; __builtin_memcpy(&h, &s, 16); return h; }

DEV float wave_sum(float v) {
    #pragma unroll
    for (int m = 1; m < 64; m <<= 1) v += __shfl_xor(v, m);
    return v;
}

// ---------------------------------------------------------------------------
// Weight prep: fold complex conv (wA = wr-wi for n<COUT, wB = wr+wi), fp16,
// MFMA fragment order: flat = ((s*NG+gg)*64+lane)*8+j, s = kc*9+tap,
// n = gg*16+(lane&15), cin = kc*32+(lane>>4)*8+j. Conv biases dropped (BN
// cancels them exactly).
// ---------------------------------------------------------------------------
__global__ __launch_bounds__(256) void prep_w_k(
    const float* __restrict__ wr, const float* __restrict__ wi,
    f16* __restrict__ wf, int CIN, int COUT)
{
    int idx = blockIdx.x * 256 + threadIdx.x;
    int KC = CIN >> 5, NG = (2 * COUT) >> 4;
    int total = 9 * KC * NG * 512;
    if (idx >= total) return;
    int j = idx & 7, lane = (idx >> 3) & 63;
    int t9 = idx >> 9;
    int gg = t9 % NG, s = t9 / NG;
    int tap = s % 9, kc = s / 9;
    int n = gg * 16 + (lane & 15);
    int cin = kc * 32 + (lane >> 4) * 8 + j;
    int o = n < COUT ? n : n - COUT;
    float sgn = n < COUT ? -1.f : 1.f;
    float wv = wr[(o * CIN + cin) * 9 + tap] + sgn * wi[(o * CIN + cin) * 9 + tap];
    wf[idx] = (f16)wv;
}

// ---------------------------------------------------------------------------
// conv1: 2 -> 64 channels, fp32 VALU, NHWC fp16 output. No bias (BN removes).
// ---------------------------------------------------------------------------
__global__ __launch_bounds__(256) void conv1_k(
    const float* __restrict__ x,
    const float* __restrict__ w1r, const float* __restrict__ w1i,
    f16* __restrict__ out)
{
    int idx = blockIdx.x * 256 + threadIdx.x;      // b*4096 + m*64 + n
    int b = idx >> 12, p = idx & 4095;
    int m = p >> 6, n = p & 63;

    float v[2][9];
    #pragma unroll
    for (int dy = 0; dy < 3; ++dy)
        #pragma unroll
        for (int dx = 0; dx < 3; ++dx) {
            int yy = m + dy - 1, xx = n + dx - 1;
            bool ok = (yy >= 0 && yy < 64 && xx >= 0 && xx < 64);
            int base = ((b * 64 + (ok ? yy : 0)) * 64 + (ok ? xx : 0)) * 2;
            v[0][dy*3+dx] = ok ? x[base]     : 0.f;
            v[1][dy*3+dx] = ok ? x[base + 1] : 0.f;
        }

    float o1[64];
    #pragma unroll
    for (int o = 0; o < 32; ++o) {
        float cr = 0.f, ci = 0.f;
        #pragma unroll
        for (int c = 0; c < 2; ++c)
            #pragma unroll
            for (int k = 0; k < 9; ++k) {
                cr = fmaf(v[c][k], w1r[(o*2+c)*9 + k], cr);
                ci = fmaf(v[c][k], w1i[(o*2+c)*9 + k], ci);
            }
        o1[o]      = cr - ci;
        o1[32 + o] = cr + ci;
    }
    f16* ob = out + (size_t)idx * 64;
    #pragma unroll
    for (int grp = 0; grp < 8; ++grp) {
        short8 pk;
        #pragma unroll
        for (int k = 0; k < 8; ++k) pk[k] = f2h(o1[grp*8 + k]);
        *(short8*)(ob + grp * 8) = pk;
    }
}

// ---------------------------------------------------------------------------
// Per-channel sum/sumsq over NHWC fp16, vectorized x8. C8 = C/8.
// ---------------------------------------------------------------------------
template<int C8>
__global__ __launch_bounds__(256) void statsv_k(
    const f16* __restrict__ t, float* __restrict__ stats, int iters)
{
    const int C = C8 * 8;
    __shared__ float ls[2 * C];
    const int tid = threadIdx.x;
    const int cg = tid & (C8 - 1), pg = tid / C8;
    const int NG = 256 / C8;
    for (int u = tid; u < 2 * C; u += 256) ls[u] = 0.f;
    __syncthreads();
    float s8[8] = {0,0,0,0,0,0,0,0}, q8[8] = {0,0,0,0,0,0,0,0};
    size_t base = (size_t)blockIdx.x * NG * iters + pg;
    for (int i = 0; i < iters; ++i) {
        size_t pp = base + (size_t)i * NG;
        short8 r = *(const short8*)(t + pp * C + cg * 8);
        #pragma unroll
        for (int k = 0; k < 8; ++k) { float v = h2f(r[k]); s8[k] += v; q8[k] += v * v; }
    }
    #pragma unroll
    for (int k = 0; k < 8; ++k) {
        atomicAdd(&ls[cg*8 + k], s8[k]);
        atomicAdd(&ls[C + cg*8 + k], q8[k]);
    }
    __syncthreads();
    for (int u = tid; u < C; u += 256) {
        atomicAdd(&stats[u], ls[u]);
        atomicAdd(&stats[C + u], ls[C + u]);
    }
}

__global__ void bnparam_k(const float* __restrict__ stats,
                          const float* __restrict__ g, const float* __restrict__ be,
                          float* __restrict__ sc, int C)
{
    int c = threadIdx.x;
    if (c >= C) return;
    const float invN = 1.f / (128.f * 4096.f);
    float mean  = stats[c] * invN;
    float var   = stats[C + c] * invN - mean * mean;
    float scale = g[c] * rsqrtf(var + 1e-5f);
    sc[c]     = scale;
    sc[C + c] = be[c] - mean * scale;
}

// ---------------------------------------------------------------------------
// Staging helpers (compile-time CNT/I0): load raw tile elems into regs, and
// later BN+relu+pack them into the (inactive) act LDS buffer.
// ---------------------------------------------------------------------------
template<int CIN, int E, int CNT, int I0>
DEV void stage_load(const f16* __restrict__ in, int b, int y0, int kq, int tid,
                    short8* raw)
{
    #pragma unroll
    for (int i = 0; i < CNT; ++i) {
        int u = tid + (I0 + i) * 512;
        if (u < E) {
            int r = u / 264, rem = u - r * 264;
            int sx = rem >> 2, cg = rem & 3;
            int srow = y0 - 1 + r, gx = sx - 1;
            if (srow >= 0 && srow < 64 && gx >= 0 && gx < 64)
                raw[i] = *(const short8*)(in +
                    ((size_t)(b*4096 + srow*64 + gx)) * CIN + kq*32 + cg*8);
        }
    }
}

template<int CIN, int E, int CNT, int I0>
DEV void stage_write(const float* __restrict__ scin, int y0, int kq, int tid,
                     const short8* raw, char* dst)
{
    half8 scl8, shf8;
    int cb = kq*32 + (tid & 3) * 8;
    #pragma unroll
    for (int k = 0; k < 8; ++k) {
        scl8[k] = (f16)scin[cb + k];
        shf8[k] = (f16)scin[CIN + cb + k];
    }
    #pragma unroll
    for (int i = 0; i < CNT; ++i) {
        int u = tid + (I0 + i) * 512;
        if (u < E) {
            int r = u / 264, rem = u - r * 264;
            int sx = rem >> 2, cg = rem & 3;
            int srow = y0 - 1 + r, gx = sx - 1;
            short8 pk = {0,0,0,0,0,0,0,0};
            if (srow >= 0 && srow < 64 && gx >= 0 && gx < 64) {
                half8 rv = s2h8(raw[i]) * scl8 + shf8;    // v_pk_fma_f16
                short8 sr; __builtin_memcpy(&sr, &rv, 16);
                pk = sr & ~(sr >> 15);                    // packed relu
            }
            int off = ((r*66 + sx)*32 + cg*8)*2 ^ ((sx & 7) << 4);
            *(short8*)(dst + off) = pk;
        }
    }
}

// ---------------------------------------------------------------------------
// Unified MFMA conv (fp16), 512-thread blocks (8 waves, 2 waves/SIMD).
// Wave = 2 rows x 64 n, acc[8][4] (32 MFMA/step burst), batched a[8] reads.
// Double-buffered act LDS: quarter kq+1's global loads are issued at the
// START of quarter kq's 9 MFMA steps (latency hides under ~10K cy of MFMA),
// BN+relu+ds_write land in the inactive buffer mid/end-quarter; ONE barrier
// per quarter. B fragments direct from global with 1-step register prefetch.
// conv2 (CHUNK=0): 8 rows x 128 n; conv3 (CHUNK=1): 16 rows x 64 n.
// ---------------------------------------------------------------------------
template<int CIN, bool CHUNK>
__global__ __launch_bounds__(512, 2) void conv_mfma_k(
    const f16* __restrict__ in, const f16* __restrict__ wf,
    const float* __restrict__ scin, f16* __restrict__ outp,
    float* __restrict__ stats, int n0, int NG, int statsC, int ostride)
{
    constexpr int KQ = CIN / 32;
    constexpr int NSTEP = KQ * 9;
    constexpr int NH   = CHUNK ? 1 : 2;
    constexpr int RW   = 8 / NH;
    constexpr int ROWS = 2 * RW;
    constexpr int SROWS = ROWS + 2;
    constexpr int YT   = 64 / ROWS;
    constexpr int E    = SROWS * 66 * 4;      // half8 stage elems
    constexpr int C    = (E + 511) / 512;     // per-thread loads
    constexpr int C0   = (C + 1) / 2, C1 = C - C0;
    constexpr int AB   = SROWS * 66 * 32 * 2; // act buffer bytes
    __shared__ char actl[2][AB];
    __shared__ float lsts[8][64], lstq[8][64];
    // XCD-chunked swizzle
    const int flat = blockIdx.x;              // [0, 128*YT)
    const int swzb = (flat & 7) * (128*YT/8) + (flat >> 3);
    const int b = swzb / YT, y0 = (swzb % YT) * ROWS;
    const int tid = threadIdx.x, l = tid & 63, w = tid >> 6;
    const int rp = w / NH, nh = w % NH;
    const int li = l & 15, g = l >> 4;

    f32x4 acc[8][4];
    #pragma unroll
    for (int mf = 0; mf < 8; ++mf)
        #pragma unroll
        for (int nf = 0; nf < 4; ++nf)
            acc[mf][nf] = f32x4{0.f, 0.f, 0.f, 0.f};

    int swz[3];
    #pragma unroll
    for (int dx = 0; dx < 3; ++dx) swz[dx] = ((li + dx) & 7) << 4;

    const f16* wblk = wf + ((size_t)((n0 >> 4) + nh*4) << 9) + (l << 3);
    auto bload = [&](int st, short8* dst) {
        const f16* p = wblk + ((size_t)(st * NG) << 9);
        #pragma unroll
        for (int nf = 0; nf < 4; ++nf) dst[nf] = *(const short8*)(p + (nf << 9));
    };
    short8 breg[4], nbreg[4];

    auto STEP = [&](int kq, int tap, const char* act) {
        int st = kq * 9 + tap;
        if (st + 1 < NSTEP) bload(st + 1, nbreg);
        int dy = (tap * 11) >> 5, dx = tap - dy * 3;
        half8 a[8];
        #pragma unroll
        for (int mf = 0; mf < 8; ++mf) {
            int r = 2*rp + (mf >> 2) + dy;
            int sx = (mf & 3)*16 + li + dx;
            a[mf] = s2h8(*(const short8*)(act + ((((r*66 + sx)*32) + g*8)*2 ^ swz[dx])));
        }
        __builtin_amdgcn_s_setprio(1);
        #pragma unroll
        for (int mf = 0; mf < 8; ++mf)
            #pragma unroll
            for (int nf = 0; nf < 4; ++nf)
                acc[mf][nf] = __builtin_amdgcn_mfma_f32_16x16x32_f16(a[mf], s2h8(breg[nf]), acc[mf][nf], 0, 0, 0);
        __builtin_amdgcn_s_setprio(0);
        #pragma unroll
        for (int nf = 0; nf < 4; ++nf) breg[nf] = nbreg[nf];
    };

    short8 rawA[C0], rawB[C1];
    // ---- prologue: stage quarter 0 into actl[0]
    stage_load <CIN, E, C0, 0 >(in, b, y0, 0, tid, rawA);
    stage_load <CIN, E, C1, C0>(in, b, y0, 0, tid, rawB);
    stage_write<CIN, E, C0, 0 >(scin, y0, 0, tid, rawA, actl[0]);
    stage_write<CIN, E, C1, C0>(scin, y0, 0, tid, rawB, actl[0]);
    __syncthreads();
    bload(0, breg);

    for (int kq = 0; kq < KQ; ++kq) {
        char* cur = actl[kq & 1];
        char* nxt = actl[(kq + 1) & 1];
        const bool pf = (kq + 1 < KQ);
        if (pf) stage_load<CIN, E, C0, 0>(in, b, y0, kq + 1, tid, rawA);
        #pragma unroll
        for (int tap = 0; tap < 4; ++tap) STEP(kq, tap, cur);
        if (pf) {
            stage_write<CIN, E, C0, 0 >(scin, y0, kq + 1, tid, rawA, nxt);
            stage_load <CIN, E, C1, C0>(in, b, y0, kq + 1, tid, rawB);
        }
        #pragma unroll
        for (int tap = 4; tap < 9; ++tap) STEP(kq, tap, cur);
        if (pf) stage_write<CIN, E, C1, C0>(scin, y0, kq + 1, tid, rawB, nxt);
        __syncthreads();
    }

    // ---- stats epilogue (pre-BN sums): reduce over px, accumulate global
    #pragma unroll
    for (int nf = 0; nf < 4; ++nf) {
        float s = 0.f, q = 0.f;
        #pragma unroll
        for (int mf = 0; mf < 8; ++mf)
            #pragma unroll
            for (int reg = 0; reg < 4; ++reg) {
                float v = acc[mf][nf][reg];
                s += v; q += v * v;
            }
        s += __shfl_xor(s, 16); s += __shfl_xor(s, 32);
        q += __shfl_xor(q, 16); q += __shfl_xor(q, 32);
        if (l < 16) { lsts[w][nf*16 + l] = s; lstq[w][nf*16 + l] = q; }
    }
    __syncthreads();
    if (tid < NH*64) {
        int ch64 = tid & 63, half = tid >> 6;
        float s = 0.f, q = 0.f;
        #pragma unroll
        for (int j = 0; j < RW; ++j) {
            s += lsts[j*NH + half][ch64];
            q += lstq[j*NH + half][ch64];
        }
        atomicAdd(&stats[tid], s);
        atomicAdd(&stats[statsC + tid], q);
    }

    // ---- store fp16
    const int obase = nh * 64;    // 0 when CHUNK
    #pragma unroll
    for (int mf = 0; mf < 8; ++mf) {
        size_t rowbase = (size_t)b * 4096 + (size_t)(y0 + 2*rp + (mf >> 2)) * 64;
        #pragma unroll
        for (int nf = 0; nf < 4; ++nf) {
            int n = obase + nf*16 + li;
            #pragma unroll
            for (int reg = 0; reg < 4; ++reg) {
                int xx = (mf & 3)*16 + g*4 + reg;
                outp[(rowbase + xx) * ostride + n] = (f16)acc[mf][nf][reg];
            }
        }
    }
}

// ---------------------------------------------------------------------------
// Pool chunk: BN+relu on fp16 chunk (64 ch), pu (row means, direct write),
// pv (col means, atomicAdd across 2 y-half blocks). grid (128, 2).
// ---------------------------------------------------------------------------
__global__ __launch_bounds__(256) void pool_k(
    const f16* __restrict__ t3c, const float* __restrict__ sc3c,
    float* __restrict__ pu, float* __restrict__ pv, int ncb)
{
    const int b = blockIdx.x, yh = blockIdx.y;
    const int t = threadIdx.x, cg = t & 7, xp = t >> 3;
    const int w = t >> 6, lane = t & 63;
    __shared__ float rq[4][16][64];
    float scl[8], shf[8];
    #pragma unroll
    for (int k = 0; k < 8; ++k) { scl[k] = sc3c[cg*8 + k]; shf[k] = sc3c[64 + cg*8 + k]; }
    float colacc[2][8];
    #pragma unroll
    for (int xi = 0; xi < 2; ++xi)
        #pragma unroll
        for (int k = 0; k < 8; ++k) colacc[xi][k] = 0.f;

    for (int yb = 0; yb < 2; ++yb) {
        for (int yy = 0; yy < 16; ++yy) {
            int y = yh*32 + yb*16 + yy;
            float rc[8];
            #pragma unroll
            for (int xi = 0; xi < 2; ++xi) {
                int xx = xp*2 + xi;
                short8 raw = *(const short8*)(t3c +
                    ((size_t)(b*4096 + y*64 + xx)) * 64 + cg*8);
                #pragma unroll
                for (int k = 0; k < 8; ++k) {
                    float v = fmaxf(fmaf(h2f(raw[k]), scl[k], shf[k]), 0.f);
                    colacc[xi][k] += v;
                    rc[k] = xi ? (rc[k] + v) : v;
                }
            }
            #pragma unroll
            for (int k = 0; k < 8; ++k) {
                rc[k] += __shfl_xor(rc[k], 8);
                rc[k] += __shfl_xor(rc[k], 16);
                rc[k] += __shfl_xor(rc[k], 32);
            }
            if (lane < 8) {
                #pragma unroll
                for (int k = 0; k < 8; ++k) rq[w][yy][lane*8 + k] = rc[k];
            }
        }
        __syncthreads();
        for (int u = t; u < 1024; u += 256) {
            int yy = u >> 6, c = u & 63;
            float v = rq[0][yy][c] + rq[1][yy][c] + rq[2][yy][c] + rq[3][yy][c];
            pu[((size_t)b*256 + ncb + c)*64 + (yh*32 + yb*16 + yy)] = v * (1.f/64.f);
        }
        __syncthreads();
    }
    #pragma unroll
    for (int xi = 0; xi < 2; ++xi)
        #pragma unroll
        for (int k = 0; k < 8; ++k)
            atomicAdd(&pv[((size_t)b*256 + ncb + cg*8 + k)*64 + xp*2 + xi],
                      colacc[xi][k] * (1.f/64.f));
}

// ---------------------------------------------------------------------------
// u/v head: out[b][o][m] = relu(sum_c pool[b][c][m] * w[o][c] + bias[o])
// ---------------------------------------------------------------------------
__global__ __launch_bounds__(256) void headuv_k(
    const float* __restrict__ pool, const float* __restrict__ w,
    const float* __restrict__ bias, float* __restrict__ out)
{
    int b = blockIdx.x;
    int m = threadIdx.x & 63;
    int ob4 = threadIdx.x >> 6;
    float acc[4] = { bias[ob4], bias[ob4+4], bias[ob4+8], bias[ob4+12] };
    const float* pb = pool + (size_t)b * 256 * 64 + m;
    for (int c = 0; c < 256; ++c) {
        float v = pb[c * 64];
        #pragma unroll
        for (int i = 0; i < 4; ++i)
            acc[i] = fmaf(v, w[(ob4 + i*4) * 256 + c], acc[i]);
    }
    float* op = out + (size_t)b * 16 * 64 + m;
    #pragma unroll
    for (int i = 0; i < 4; ++i)
        op[(ob4 + i*4) * 64] = fmaxf(acc[i], 0.f);
}

// s head: ps derived from pu (ps[b][c] = mean_m pu[b][c][m]); 1 wave per b.
__global__ __launch_bounds__(64) void heads_s_k(
    const float* __restrict__ pu, const float* __restrict__ wS,
    const float* __restrict__ bS, float* __restrict__ out)
{
    int b = blockIdx.x, lane = threadIdx.x;
    __shared__ float ls[256];
    for (int i = 0; i < 4; ++i) {
        const float* p = pu + ((size_t)b*256 + lane*4 + i) * 64;
        float s = 0.f;
        for (int m = 0; m < 64; ++m) s += p[m];
        ls[lane*4 + i] = s * (1.f/64.f);
    }
    __syncthreads();
    float acc[8] = {0,0,0,0,0,0,0,0};
    for (int c = lane; c < 256; c += 64) {
        float v = ls[c];
        #pragma unroll
        for (int o = 0; o < 8; ++o) acc[o] = fmaf(v, wS[o*256 + c], acc[o]);
    }
    #pragma unroll
    for (int o = 0; o < 8; ++o) acc[o] = wave_sum(acc[o]);
    if (lane == 0) {
        #pragma unroll
        for (int o = 0; o < 8; ++o)
            out[b*8 + o] = fmaxf(acc[o] + bS[o], 0.f);
    }
}

// ---------------------------------------------------------------------------
// Gram-Schmidt: one wave per batch, lane = m. pre: (B,16,64), out: (B,64,8,2)
// ---------------------------------------------------------------------------
__global__ __launch_bounds__(64) void gs_k(
    const float* __restrict__ pre, float* __restrict__ out)
{
    int b = blockIdx.x, lane = threadIdx.x;
    const float* pb = pre + (size_t)b * 16 * 64 + lane;
    float vr[8], vi[8], den[8];
    #pragma unroll
    for (int j = 0; j < 8; ++j) { vr[j] = pb[(2*j)*64]; vi[j] = pb[(2*j+1)*64]; }

    #pragma unroll
    for (int j = 0; j < 8; ++j) {
        #pragma unroll
        for (int k = 0; k < j; ++k) {
            float d = wave_sum(vr[j]*vr[k] + vi[j]*vi[k]);
            float coef = d / den[k];
            vr[j] = fmaf(-coef, vr[k], vr[j]);
            vi[j] = fmaf(-coef, vi[k], vi[j]);
        }
        float n2 = wave_sum(vr[j]*vr[j] + vi[j]*vi[j]);
        float inv = 1.f / sqrtf(n2 + 1e-8f);
        vr[j] *= inv; vi[j] *= inv;
        float nn = wave_sum(vr[j]*vr[j] + vi[j]*vi[j]);
        den[j] = nn + 1e-8f;
    }
    float* ob = out + (size_t)b * 64 * 16 + lane * 16;
    #pragma unroll
    for (int j = 0; j < 8; ++j) { ob[j*2] = vr[j]; ob[j*2+1] = vi[j]; }
}

// ---------------------------------------------------------------------------
extern "C" void kernel_launch(void* const* d_in, const int* in_sizes, int n_in,
                              void* d_out, int out_size, void* d_ws, size_t ws_size,
                              hipStream_t stream)
{
    const float* x   = (const float*)d_in[0];
    const float* w1r = (const float*)d_in[1];
    const float* w1i = (const float*)d_in[3];
    const float* g1  = (const float*)d_in[5];
    const float* be1 = (const float*)d_in[6];
    const float* w2r = (const float*)d_in[7];
    const float* w2i = (const float*)d_in[9];
    const float* g2  = (const float*)d_in[11];
    const float* be2 = (const float*)d_in[12];
    const float* w3r = (const float*)d_in[13];
    const float* w3i = (const float*)d_in[15];
    const float* g3  = (const float*)d_in[17];
    const float* be3 = (const float*)d_in[18];
    const float* wu  = (const float*)d_in[19];
    const float* bu  = (const float*)d_in[20];
    const float* wS  = (const float*)d_in[21];
    const float* bS  = (const float*)d_in[22];
    const float* wv  = (const float*)d_in[23];
    const float* bv  = (const float*)d_in[24];
    float* out = (float*)d_out;

    char* ws = (char*)d_ws;
    // Layout, total 219,290,624 B == proven-safe footprint (r2-r13).
    f16*   t2     = (f16*)  (ws + 0);            // 134,217,728
    f16*   t1     = (f16*)  (ws + 134217728);    //  67,108,864 (dead after conv2)
    f16*   t3c    = (f16*)  (ws + 134217728);    //  67,108,864 (overlays t1)
    float* upre   = (float*)(ws + 134217728);    // 524,288 (after pools; t3c dead)
    float* vpre   = (float*)(ws + 134742016);    // 524,288
    float* pu     = (float*)(ws + 201326592);    //   8,388,608
    float* pv     = (float*)(ws + 209715200);    //   8,388,608
    // wreg region: wfrag2 (147,456 B) then wfrag3 (589,824 B)
    f16*   wfrag2 = (f16*)  (ws + 218103808);
    f16*   wfrag3 = (f16*)  (ws + 218103808);    // ends < 219,283,456
    float* stats  = (float*)(ws + 219283456);    // 896 floats (3584 B)
    float* scsh   = (float*)(ws + 219287040);    // 512 floats
    // stats layout: s1 [0,128), s2 [128,384), s3 chunk nc at [384+nc*128)
    float* stats1 = stats,  *stats2 = stats + 128;
    float* sc1    = scsh,   *sc2    = scsh  + 128, *sc3c = scsh + 384;

    hipMemsetAsync(stats, 0, 3584, stream);
    hipMemsetAsync(pv, 0, (size_t)128*256*64*4, stream);

    // ---- weight prep for conv2 (9*2*8*512 = 73728 elems)
    prep_w_k<<<288, 256, 0, stream>>>(w2r, w2i, wfrag2, 64, 64);

    // ---- layer 1
    conv1_k<<<2048, 256, 0, stream>>>(x, w1r, w1i, t1);
    statsv_k<8><<<1024, 256, 0, stream>>>(t1, stats1, 16);
    bnparam_k<<<1, 64, 0, stream>>>(stats1, g1, be1, sc1, 64);

    // ---- layer 2 (BN1+relu fused in staging; stats fused in epilogue)
    conv_mfma_k<64, false><<<1024, 512, 0, stream>>>(
        t1, wfrag2, sc1, t2, stats2,
        /*n0=*/0, /*NG=*/8, /*statsC=*/128, /*ostride=*/128);
    bnparam_k<<<1, 128, 0, stream>>>(stats2, g2, be2, sc2, 128);

    // ---- layer 3: conv once, 4 chunks of 64 out-ch (chunk in fp16)
    prep_w_k<<<1152, 256, 0, stream>>>(w3r, w3i, wfrag3, 128, 128);
    for (int nc = 0; nc < 4; ++nc) {
        conv_mfma_k<128, true><<<512, 512, 0, stream>>>(
            t2, wfrag3, sc2, t3c, stats + 384 + nc*128,
            /*n0=*/nc*64, /*NG=*/16, /*statsC=*/64, /*ostride=*/64);
        bnparam_k<<<1, 64, 0, stream>>>(stats + 384 + nc*128, g3 + nc*64, be3 + nc*64, sc3c, 64);
        pool_k<<<dim3(128, 2), 256, 0, stream>>>(t3c, sc3c, pu, pv, nc*64);
    }

    // ---- heads
    headuv_k<<<128, 256, 0, stream>>>(pu, wu, bu, upre);
    headuv_k<<<128, 256, 0, stream>>>(pv, wv, bv, vpre);
    heads_s_k<<<128, 64, 0, stream>>>(pu, wS, bS, out + 131072);

    // ---- gram-schmidt
    gs_k<<<128, 64, 0, stream>>>(upre, out);            // u at [0, 131072)
    gs_k<<<128, 64, 0, stream>>>(vpre, out + 132096);   // v at [132096, 263168)
}

// Round 15
// 741.687 us; speedup vs baseline: 2.3140x; 2.3140x over previous
//
#include <hip/hip_runtime.h>

typedef _Float16 f16;
typedef __attribute__((ext_vector_type(8))) short short8;
typedef __attribute__((ext_vector_type(8))) _Float16 half8;
typedef __attribute__((ext_vector_type(4))) float f32x4;

#define DEV __device__ __forceinline__

DEV float h2f(short s) { f16 h; __builtin_memcpy(&h, &s, 2); return (float)h; }
DEV short f2h(float f) { f16 h = (f16)f; short s; __builtin_memcpy(&s, &h, 2); return s; }
DEV half8 s2h8(short8 s) { half8 h; __builtin_memcpy(&h, &s, 16); return h; }

DEV float wave_sum(float v) {
    #pragma unroll
    for (int m = 1; m < 64; m <<= 1) v += __shfl_xor(v, m);
    return v;
}

// ---------------------------------------------------------------------------
// Weight prep: fold complex conv (wA = wr-wi for n<COUT, wB = wr+wi), fp16,
// MFMA fragment order: flat = ((s*NG+gg)*64+lane)*8+j, s = kc*9+tap,
// n = gg*16+(lane&15), cin = kc*32+(lane>>4)*8+j. Conv biases dropped (BN
// cancels them exactly).
// ---------------------------------------------------------------------------
__global__ __launch_bounds__(256) void prep_w_k(
    const float* __restrict__ wr, const float* __restrict__ wi,
    f16* __restrict__ wf, int CIN, int COUT)
{
    int idx = blockIdx.x * 256 + threadIdx.x;
    int KC = CIN >> 5, NG = (2 * COUT) >> 4;
    int total = 9 * KC * NG * 512;
    if (idx >= total) return;
    int j = idx & 7, lane = (idx >> 3) & 63;
    int t9 = idx >> 9;
    int gg = t9 % NG, s = t9 / NG;
    int tap = s % 9, kc = s / 9;
    int n = gg * 16 + (lane & 15);
    int cin = kc * 32 + (lane >> 4) * 8 + j;
    int o = n < COUT ? n : n - COUT;
    float sgn = n < COUT ? -1.f : 1.f;
    float wv = wr[(o * CIN + cin) * 9 + tap] + sgn * wi[(o * CIN + cin) * 9 + tap];
    wf[idx] = (f16)wv;
}

// ---------------------------------------------------------------------------
// conv1: 2 -> 64 channels, fp32 VALU, NHWC fp16 output. No bias (BN removes).
// ---------------------------------------------------------------------------
__global__ __launch_bounds__(256) void conv1_k(
    const float* __restrict__ x,
    const float* __restrict__ w1r, const float* __restrict__ w1i,
    f16* __restrict__ out)
{
    int idx = blockIdx.x * 256 + threadIdx.x;      // b*4096 + m*64 + n
    int b = idx >> 12, p = idx & 4095;
    int m = p >> 6, n = p & 63;

    float v[2][9];
    #pragma unroll
    for (int dy = 0; dy < 3; ++dy)
        #pragma unroll
        for (int dx = 0; dx < 3; ++dx) {
            int yy = m + dy - 1, xx = n + dx - 1;
            bool ok = (yy >= 0 && yy < 64 && xx >= 0 && xx < 64);
            int base = ((b * 64 + (ok ? yy : 0)) * 64 + (ok ? xx : 0)) * 2;
            v[0][dy*3+dx] = ok ? x[base]     : 0.f;
            v[1][dy*3+dx] = ok ? x[base + 1] : 0.f;
        }

    float o1[64];
    #pragma unroll
    for (int o = 0; o < 32; ++o) {
        float cr = 0.f, ci = 0.f;
        #pragma unroll
        for (int c = 0; c < 2; ++c)
            #pragma unroll
            for (int k = 0; k < 9; ++k) {
                cr = fmaf(v[c][k], w1r[(o*2+c)*9 + k], cr);
                ci = fmaf(v[c][k], w1i[(o*2+c)*9 + k], ci);
            }
        o1[o]      = cr - ci;
        o1[32 + o] = cr + ci;
    }
    f16* ob = out + (size_t)idx * 64;
    #pragma unroll
    for (int grp = 0; grp < 8; ++grp) {
        short8 pk;
        #pragma unroll
        for (int k = 0; k < 8; ++k) pk[k] = f2h(o1[grp*8 + k]);
        *(short8*)(ob + grp * 8) = pk;
    }
}

// ---------------------------------------------------------------------------
// Per-channel sum/sumsq over NHWC fp16, vectorized x8. C8 = C/8.
// ---------------------------------------------------------------------------
template<int C8>
__global__ __launch_bounds__(256) void statsv_k(
    const f16* __restrict__ t, float* __restrict__ stats, int iters)
{
    const int C = C8 * 8;
    __shared__ float ls[2 * C];
    const int tid = threadIdx.x;
    const int cg = tid & (C8 - 1), pg = tid / C8;
    const int NG = 256 / C8;
    for (int u = tid; u < 2 * C; u += 256) ls[u] = 0.f;
    __syncthreads();
    float s8[8] = {0,0,0,0,0,0,0,0}, q8[8] = {0,0,0,0,0,0,0,0};
    size_t base = (size_t)blockIdx.x * NG * iters + pg;
    for (int i = 0; i < iters; ++i) {
        size_t pp = base + (size_t)i * NG;
        short8 r = *(const short8*)(t + pp * C + cg * 8);
        #pragma unroll
        for (int k = 0; k < 8; ++k) { float v = h2f(r[k]); s8[k] += v; q8[k] += v * v; }
    }
    #pragma unroll
    for (int k = 0; k < 8; ++k) {
        atomicAdd(&ls[cg*8 + k], s8[k]);
        atomicAdd(&ls[C + cg*8 + k], q8[k]);
    }
    __syncthreads();
    for (int u = tid; u < C; u += 256) {
        atomicAdd(&stats[u], ls[u]);
        atomicAdd(&stats[C + u], ls[C + u]);
    }
}

__global__ void bnparam_k(const float* __restrict__ stats,
                          const float* __restrict__ g, const float* __restrict__ be,
                          float* __restrict__ sc, int C)
{
    int c = threadIdx.x;
    if (c >= C) return;
    const float invN = 1.f / (128.f * 4096.f);
    float mean  = stats[c] * invN;
    float var   = stats[C + c] * invN - mean * mean;
    float scale = g[c] * rsqrtf(var + 1e-5f);
    sc[c]     = scale;
    sc[C + c] = be[c] - mean * scale;
}

// ---------------------------------------------------------------------------
// Unified MFMA conv (fp16), 512-thread blocks (8 waves, 2 waves/SIMD).
// Wave = 2 rows x 64 n, acc[8][4] (32 MFMA/step burst) with BATCHED a[8]
// ds_reads (one exposed LDS latency per step instead of eight). Act staged
// per 32-ch quarter (single-buffer LDS, swizzled). B fragments direct from
// global (L2-resident) with 1-step register prefetch. s_setprio around the
// burst. conv2 (CHUNK=0): 8 rows x 128 n; conv3 (CHUNK=1): 16 rows x 64 n.
// ---------------------------------------------------------------------------
template<int CIN, bool CHUNK>
__global__ __launch_bounds__(512, 2) void conv_mfma_k(
    const f16* __restrict__ in, const f16* __restrict__ wf,
    const float* __restrict__ scin, f16* __restrict__ outp,
    float* __restrict__ stats, int n0, int NG, int statsC, int ostride)
{
    constexpr int KQ = CIN / 32;
    constexpr int NSTEP = KQ * 9;
    constexpr int NH   = CHUNK ? 1 : 2;       // n-halves per block
    constexpr int RW   = 8 / NH;              // row-pairs per block
    constexpr int ROWS = 2 * RW;              // output rows per block
    constexpr int SROWS = ROWS + 2;           // staged rows (halo)
    constexpr int YT   = 64 / ROWS;           // y-tiles per image
    __shared__ char actl[SROWS*66*32*2];
    __shared__ float lsts[8][64], lstq[8][64];
    // XCD-chunked swizzle
    const int flat = blockIdx.x;              // [0, 128*YT)
    const int swzb = (flat & 7) * (128*YT/8) + (flat >> 3);
    const int b = swzb / YT, y0 = (swzb % YT) * ROWS;
    const int tid = threadIdx.x, l = tid & 63, w = tid >> 6;
    const int rp = w / NH, nh = w % NH;
    const int li = l & 15, g = l >> 4;

    f32x4 acc[8][4];
    #pragma unroll
    for (int mf = 0; mf < 8; ++mf)
        #pragma unroll
        for (int nf = 0; nf < 4; ++nf)
            acc[mf][nf] = f32x4{0.f, 0.f, 0.f, 0.f};

    int swz[3];
    #pragma unroll
    for (int dx = 0; dx < 3; ++dx) swz[dx] = ((li + dx) & 7) << 4;

    const f16* wblk = wf + ((size_t)((n0 >> 4) + nh*4) << 9) + (l << 3);
    auto bload = [&](int st, short8* dst) {
        const f16* p = wblk + ((size_t)(st * NG) << 9);   // s == st (kc-outer layout)
        #pragma unroll
        for (int nf = 0; nf < 4; ++nf) dst[nf] = *(const short8*)(p + (nf << 9));
    };
    short8 breg[4], nbreg[4];
    bload(0, breg);

    for (int st = 0; st < NSTEP; ++st) {
        const int kq = st / 9, tap = st - kq * 9;
        if (tap == 0) {
            half8 scl8, shf8;
            {
                int cb = kq*32 + (tid & 3) * 8;
                #pragma unroll
                for (int k = 0; k < 8; ++k) {
                    scl8[k] = (f16)scin[cb + k];
                    shf8[k] = (f16)scin[CIN + cb + k];
                }
            }
            __syncthreads();
            // stage act quarter kq: rows y0-1..y0+ROWS, ch [kq*32, kq*32+32)
            #pragma unroll
            for (int i = 0; i < (SROWS*66*4 + 511)/512; ++i) {
                int u = tid + i * 512;
                if (u < SROWS*66*4) {
                    int r = u / 264, rem = u - r * 264;
                    int sx = rem >> 2, cg = rem & 3;
                    int srow = y0 - 1 + r, gx = sx - 1;
                    short8 pk = {0,0,0,0,0,0,0,0};
                    if (srow >= 0 && srow < 64 && gx >= 0 && gx < 64) {
                        short8 raw = *(const short8*)(in +
                            ((size_t)(b*4096 + srow*64 + gx)) * CIN + kq*32 + cg*8);
                        half8 rv = s2h8(raw) * scl8 + shf8;   // v_pk_fma_f16
                        short8 sr; __builtin_memcpy(&sr, &rv, 16);
                        pk = sr & ~(sr >> 15);                // packed relu
                    }
                    int off = ((r*66 + sx)*32 + cg*8)*2 ^ ((sx & 7) << 4);
                    *(short8*)(actl + off) = pk;
                }
            }
            __syncthreads();
        }
        if (st + 1 < NSTEP) bload(st + 1, nbreg);
        int dy = (tap * 11) >> 5, dx = tap - dy * 3;
        // batched A reads: 8 ds_read_b128 back-to-back, one exposed latency
        half8 a[8];
        #pragma unroll
        for (int mf = 0; mf < 8; ++mf) {
            int r = 2*rp + (mf >> 2) + dy;
            int sx = (mf & 3)*16 + li + dx;
            a[mf] = s2h8(*(const short8*)(actl + ((((r*66 + sx)*32) + g*8)*2 ^ swz[dx])));
        }
        __builtin_amdgcn_s_setprio(1);
        #pragma unroll
        for (int mf = 0; mf < 8; ++mf)
            #pragma unroll
            for (int nf = 0; nf < 4; ++nf)
                acc[mf][nf] = __builtin_amdgcn_mfma_f32_16x16x32_f16(a[mf], s2h8(breg[nf]), acc[mf][nf], 0, 0, 0);
        __builtin_amdgcn_s_setprio(0);
        #pragma unroll
        for (int nf = 0; nf < 4; ++nf) breg[nf] = nbreg[nf];
    }

    // ---- stats epilogue (pre-BN sums): reduce over px, accumulate global
    #pragma unroll
    for (int nf = 0; nf < 4; ++nf) {
        float s = 0.f, q = 0.f;
        #pragma unroll
        for (int mf = 0; mf < 8; ++mf)
            #pragma unroll
            for (int reg = 0; reg < 4; ++reg) {
                float v = acc[mf][nf][reg];
                s += v; q += v * v;
            }
        s += __shfl_xor(s, 16); s += __shfl_xor(s, 32);
        q += __shfl_xor(q, 16); q += __shfl_xor(q, 32);
        if (l < 16) { lsts[w][nf*16 + l] = s; lstq[w][nf*16 + l] = q; }
    }
    __syncthreads();
    if (tid < NH*64) {
        int ch64 = tid & 63, half = tid >> 6;
        float s = 0.f, q = 0.f;
        #pragma unroll
        for (int j = 0; j < RW; ++j) {
            s += lsts[j*NH + half][ch64];
            q += lstq[j*NH + half][ch64];
        }
        atomicAdd(&stats[tid], s);
        atomicAdd(&stats[statsC + tid], q);
    }

    // ---- store fp16
    const int obase = nh * 64;    // 0 when CHUNK
    #pragma unroll
    for (int mf = 0; mf < 8; ++mf) {
        size_t rowbase = (size_t)b * 4096 + (size_t)(y0 + 2*rp + (mf >> 2)) * 64;
        #pragma unroll
        for (int nf = 0; nf < 4; ++nf) {
            int n = obase + nf*16 + li;
            #pragma unroll
            for (int reg = 0; reg < 4; ++reg) {
                int xx = (mf & 3)*16 + g*4 + reg;
                outp[(rowbase + xx) * ostride + n] = (f16)acc[mf][nf][reg];
            }
        }
    }
}

// ---------------------------------------------------------------------------
// Pool chunk: BN+relu on fp16 chunk (64 ch), pu (row means, direct write),
// pv (col means, atomicAdd across 2 y-half blocks). grid (128, 2).
// ---------------------------------------------------------------------------
__global__ __launch_bounds__(256) void pool_k(
    const f16* __restrict__ t3c, const float* __restrict__ sc3c,
    float* __restrict__ pu, float* __restrict__ pv, int ncb)
{
    const int b = blockIdx.x, yh = blockIdx.y;
    const int t = threadIdx.x, cg = t & 7, xp = t >> 3;
    const int w = t >> 6, lane = t & 63;
    __shared__ float rq[4][16][64];
    float scl[8], shf[8];
    #pragma unroll
    for (int k = 0; k < 8; ++k) { scl[k] = sc3c[cg*8 + k]; shf[k] = sc3c[64 + cg*8 + k]; }
    float colacc[2][8];
    #pragma unroll
    for (int xi = 0; xi < 2; ++xi)
        #pragma unroll
        for (int k = 0; k < 8; ++k) colacc[xi][k] = 0.f;

    for (int yb = 0; yb < 2; ++yb) {
        for (int yy = 0; yy < 16; ++yy) {
            int y = yh*32 + yb*16 + yy;
            float rc[8];
            #pragma unroll
            for (int xi = 0; xi < 2; ++xi) {
                int xx = xp*2 + xi;
                short8 raw = *(const short8*)(t3c +
                    ((size_t)(b*4096 + y*64 + xx)) * 64 + cg*8);
                #pragma unroll
                for (int k = 0; k < 8; ++k) {
                    float v = fmaxf(fmaf(h2f(raw[k]), scl[k], shf[k]), 0.f);
                    colacc[xi][k] += v;
                    rc[k] = xi ? (rc[k] + v) : v;
                }
            }
            #pragma unroll
            for (int k = 0; k < 8; ++k) {
                rc[k] += __shfl_xor(rc[k], 8);
                rc[k] += __shfl_xor(rc[k], 16);
                rc[k] += __shfl_xor(rc[k], 32);
            }
            if (lane < 8) {
                #pragma unroll
                for (int k = 0; k < 8; ++k) rq[w][yy][lane*8 + k] = rc[k];
            }
        }
        __syncthreads();
        for (int u = t; u < 1024; u += 256) {
            int yy = u >> 6, c = u & 63;
            float v = rq[0][yy][c] + rq[1][yy][c] + rq[2][yy][c] + rq[3][yy][c];
            pu[((size_t)b*256 + ncb + c)*64 + (yh*32 + yb*16 + yy)] = v * (1.f/64.f);
        }
        __syncthreads();
    }
    #pragma unroll
    for (int xi = 0; xi < 2; ++xi)
        #pragma unroll
        for (int k = 0; k < 8; ++k)
            atomicAdd(&pv[((size_t)b*256 + ncb + cg*8 + k)*64 + xp*2 + xi],
                      colacc[xi][k] * (1.f/64.f));
}

// ---------------------------------------------------------------------------
// u/v head: out[b][o][m] = relu(sum_c pool[b][c][m] * w[o][c] + bias[o])
// ---------------------------------------------------------------------------
__global__ __launch_bounds__(256) void headuv_k(
    const float* __restrict__ pool, const float* __restrict__ w,
    const float* __restrict__ bias, float* __restrict__ out)
{
    int b = blockIdx.x;
    int m = threadIdx.x & 63;
    int ob4 = threadIdx.x >> 6;
    float acc[4] = { bias[ob4], bias[ob4+4], bias[ob4+8], bias[ob4+12] };
    const float* pb = pool + (size_t)b * 256 * 64 + m;
    for (int c = 0; c < 256; ++c) {
        float v = pb[c * 64];
        #pragma unroll
        for (int i = 0; i < 4; ++i)
            acc[i] = fmaf(v, w[(ob4 + i*4) * 256 + c], acc[i]);
    }
    float* op = out + (size_t)b * 16 * 64 + m;
    #pragma unroll
    for (int i = 0; i < 4; ++i)
        op[(ob4 + i*4) * 64] = fmaxf(acc[i], 0.f);
}

// s head: ps derived from pu (ps[b][c] = mean_m pu[b][c][m]); 1 wave per b.
__global__ __launch_bounds__(64) void heads_s_k(
    const float* __restrict__ pu, const float* __restrict__ wS,
    const float* __restrict__ bS, float* __restrict__ out)
{
    int b = blockIdx.x, lane = threadIdx.x;
    __shared__ float ls[256];
    for (int i = 0; i < 4; ++i) {
        const float* p = pu + ((size_t)b*256 + lane*4 + i) * 64;
        float s = 0.f;
        for (int m = 0; m < 64; ++m) s += p[m];
        ls[lane*4 + i] = s * (1.f/64.f);
    }
    __syncthreads();
    float acc[8] = {0,0,0,0,0,0,0,0};
    for (int c = lane; c < 256; c += 64) {
        float v = ls[c];
        #pragma unroll
        for (int o = 0; o < 8; ++o) acc[o] = fmaf(v, wS[o*256 + c], acc[o]);
    }
    #pragma unroll
    for (int o = 0; o < 8; ++o) acc[o] = wave_sum(acc[o]);
    if (lane == 0) {
        #pragma unroll
        for (int o = 0; o < 8; ++o)
            out[b*8 + o] = fmaxf(acc[o] + bS[o], 0.f);
    }
}

// ---------------------------------------------------------------------------
// Gram-Schmidt: one wave per batch, lane = m. pre: (B,16,64), out: (B,64,8,2)
// ---------------------------------------------------------------------------
__global__ __launch_bounds__(64) void gs_k(
    const float* __restrict__ pre, float* __restrict__ out)
{
    int b = blockIdx.x, lane = threadIdx.x;
    const float* pb = pre + (size_t)b * 16 * 64 + lane;
    float vr[8], vi[8], den[8];
    #pragma unroll
    for (int j = 0; j < 8; ++j) { vr[j] = pb[(2*j)*64]; vi[j] = pb[(2*j+1)*64]; }

    #pragma unroll
    for (int j = 0; j < 8; ++j) {
        #pragma unroll
        for (int k = 0; k < j; ++k) {
            float d = wave_sum(vr[j]*vr[k] + vi[j]*vi[k]);
            float coef = d / den[k];
            vr[j] = fmaf(-coef, vr[k], vr[j]);
            vi[j] = fmaf(-coef, vi[k], vi[j]);
        }
        float n2 = wave_sum(vr[j]*vr[j] + vi[j]*vi[j]);
        float inv = 1.f / sqrtf(n2 + 1e-8f);
        vr[j] *= inv; vi[j] *= inv;
        float nn = wave_sum(vr[j]*vr[j] + vi[j]*vi[j]);
        den[j] = nn + 1e-8f;
    }
    float* ob = out + (size_t)b * 64 * 16 + lane * 16;
    #pragma unroll
    for (int j = 0; j < 8; ++j) { ob[j*2] = vr[j]; ob[j*2+1] = vi[j]; }
}

// ---------------------------------------------------------------------------
extern "C" void kernel_launch(void* const* d_in, const int* in_sizes, int n_in,
                              void* d_out, int out_size, void* d_ws, size_t ws_size,
                              hipStream_t stream)
{
    const float* x   = (const float*)d_in[0];
    const float* w1r = (const float*)d_in[1];
    const float* w1i = (const float*)d_in[3];
    const float* g1  = (const float*)d_in[5];
    const float* be1 = (const float*)d_in[6];
    const float* w2r = (const float*)d_in[7];
    const float* w2i = (const float*)d_in[9];
    const float* g2  = (const float*)d_in[11];
    const float* be2 = (const float*)d_in[12];
    const float* w3r = (const float*)d_in[13];
    const float* w3i = (const float*)d_in[15];
    const float* g3  = (const float*)d_in[17];
    const float* be3 = (const float*)d_in[18];
    const float* wu  = (const float*)d_in[19];
    const float* bu  = (const float*)d_in[20];
    const float* wS  = (const float*)d_in[21];
    const float* bS  = (const float*)d_in[22];
    const float* wv  = (const float*)d_in[23];
    const float* bv  = (const float*)d_in[24];
    float* out = (float*)d_out;

    char* ws = (char*)d_ws;
    // Layout, total 219,290,624 B == proven-safe footprint (r2-r14).
    f16*   t2     = (f16*)  (ws + 0);            // 134,217,728
    f16*   t1     = (f16*)  (ws + 134217728);    //  67,108,864 (dead after conv2)
    f16*   t3c    = (f16*)  (ws + 134217728);    //  67,108,864 (overlays t1)
    float* upre   = (float*)(ws + 134217728);    // 524,288 (after pools; t3c dead)
    float* vpre   = (float*)(ws + 134742016);    // 524,288
    float* pu     = (float*)(ws + 201326592);    //   8,388,608
    float* pv     = (float*)(ws + 209715200);    //   8,388,608
    // wreg region: wfrag2 (147,456 B) then wfrag3 (589,824 B)
    f16*   wfrag2 = (f16*)  (ws + 218103808);
    f16*   wfrag3 = (f16*)  (ws + 218103808);    // ends < 219,283,456
    float* stats  = (float*)(ws + 219283456);    // 896 floats (3584 B)
    float* scsh   = (float*)(ws + 219287040);    // 512 floats
    // stats layout: s1 [0,128), s2 [128,384), s3 chunk nc at [384+nc*128)
    float* stats1 = stats,  *stats2 = stats + 128;
    float* sc1    = scsh,   *sc2    = scsh  + 128, *sc3c = scsh + 384;

    hipMemsetAsync(stats, 0, 3584, stream);
    hipMemsetAsync(pv, 0, (size_t)128*256*64*4, stream);

    // ---- weight prep for conv2 (9*2*8*512 = 73728 elems)
    prep_w_k<<<288, 256, 0, stream>>>(w2r, w2i, wfrag2, 64, 64);

    // ---- layer 1
    conv1_k<<<2048, 256, 0, stream>>>(x, w1r, w1i, t1);
    statsv_k<8><<<1024, 256, 0, stream>>>(t1, stats1, 16);
    bnparam_k<<<1, 64, 0, stream>>>(stats1, g1, be1, sc1, 64);

    // ---- layer 2 (BN1+relu fused in staging; stats fused in epilogue)
    conv_mfma_k<64, false><<<1024, 512, 0, stream>>>(
        t1, wfrag2, sc1, t2, stats2,
        /*n0=*/0, /*NG=*/8, /*statsC=*/128, /*ostride=*/128);
    bnparam_k<<<1, 128, 0, stream>>>(stats2, g2, be2, sc2, 128);

    // ---- layer 3: conv once, 4 chunks of 64 out-ch (chunk in fp16)
    prep_w_k<<<1152, 256, 0, stream>>>(w3r, w3i, wfrag3, 128, 128);
    for (int nc = 0; nc < 4; ++nc) {
        conv_mfma_k<128, true><<<512, 512, 0, stream>>>(
            t2, wfrag3, sc2, t3c, stats + 384 + nc*128,
            /*n0=*/nc*64, /*NG=*/16, /*statsC=*/64, /*ostride=*/64);
        bnparam_k<<<1, 64, 0, stream>>>(stats + 384 + nc*128, g3 + nc*64, be3 + nc*64, sc3c, 64);
        pool_k<<<dim3(128, 2), 256, 0, stream>>>(t3c, sc3c, pu, pv, nc*64);
    }

    // ---- heads
    headuv_k<<<128, 256, 0, stream>>>(pu, wu, bu, upre);
    headuv_k<<<128, 256, 0, stream>>>(pv, wv, bv, vpre);
    heads_s_k<<<128, 64, 0, stream>>>(pu, wS, bS, out + 131072);

    // ---- gram-schmidt
    gs_k<<<128, 64, 0, stream>>>(upre, out);            // u at [0, 131072)
    gs_k<<<128, 64, 0, stream>>>(vpre, out + 132096);   // v at [132096, 263168)
}